// Round 8
// baseline (661.250 us; speedup 1.0000x reference)
//
#include <hip/hip_runtime.h>
#include <hip/hip_cooperative_groups.h>
#include <math.h>

namespace cg = cooperative_groups;

#define CDIM 8192
#define DDIM 512
#define NEGF -3.0e38f
#define POSF  3.0e38f

#define BM 128
#define NSLOT (CDIM / BM) /* 64 col-slots of 128 per row */

typedef __attribute__((ext_vector_type(8))) short bf16x8;
typedef __attribute__((ext_vector_type(4))) float f32x4;

__device__ __forceinline__ unsigned short f2bf(float x) {
    unsigned int u = __float_as_uint(x);
    u += 0x7fffu + ((u >> 16) & 1u);
    return (unsigned short)(u >> 16);
}
__device__ __forceinline__ float bf2f(unsigned short h) {
    return __uint_as_float(((unsigned int)h) << 16);
}
// async global->LDS, 16B per lane. LDS dest is wave-uniform base + lane*16.
__device__ __forceinline__ void gld16(const void* g, void* l) {
    __builtin_amdgcn_global_load_lds(
        (__attribute__((address_space(1))) void*)(void*)g,
        (__attribute__((address_space(3))) void*)l, 16, 0, 0);
}

// Off-diag super-tile assignment table: code = SI*8+SJ (SI<SJ, 8x8 super
// grid over the 64x64 tile grid). XCD0-3: 3 supers each (idx xcd*3+sup);
// XCD4-7: 4 supers each (idx 12+(xcd-4)*4+sup). Greedy-balanced:
// XCD0-3 also carry 2 diagonal supers (36 tiles) -> 264 tiles; XCD4-7: 256.
__device__ __constant__ unsigned char OSUP[28] = {
    1, 2, 10,   3, 11, 19,   4, 12, 20,   28, 5, 13,
    21, 29, 37, 6,   14, 22, 30, 38,   46, 7, 15, 23,   31, 39, 47, 55};

// (xcd, off) -> tile (I,J). off must be < 264 (xcd<4) / 256 (xcd>=4).
__device__ __forceinline__ void tile_map(int xcd, int off, int& I, int& J) {
    if (xcd < 4) {
        if (off < 72) {  // two diagonal supers: s = xcd*2 + (off>=36)
            const int s = xcd * 2 + (off >= 36);
            const int u = (off >= 36) ? off - 36 : off;
            int jj = 0;  // triangular: i<=j within the 8x8 super, i fastest
            while ((jj + 1) * (jj + 2) / 2 <= u) ++jj;
            const int ii = u - jj * (jj + 1) / 2;
            I = s * 8 + ii; J = s * 8 + jj;
        } else {
            const int sup = (off - 72) >> 6;
            const int u = (off - 72) & 63;
            const int code = OSUP[xcd * 3 + sup];
            I = (code >> 3) * 8 + (u & 7);   // I fastest: B-tile shared x8
            J = (code & 7) * 8 + (u >> 3);
        }
    } else {
        const int sup = off >> 6;
        const int u = off & 63;
        const int code = OSUP[12 + (xcd - 4) * 4 + sup];
        I = (code >> 3) * 8 + (u & 7);
        J = (code & 7) * 8 + (u >> 3);
    }
}

// ============ shared device bodies (fused + fallback use the SAME code,
// ============ so both paths are numerically identical) ============

// normalize row of G, split into bf16 hi/lo. All 64 lanes of a wave call.
__device__ __forceinline__ void prep_row(const float* __restrict__ g,
                                         unsigned short* __restrict__ hi,
                                         unsigned short* __restrict__ lo,
                                         int row, int lane) {
    const float4* src = (const float4*)(g + (size_t)row * DDIM);
    const float4 a = src[lane * 2];
    const float4 b = src[lane * 2 + 1];
    float s = a.x * a.x + a.y * a.y + a.z * a.z + a.w * a.w +
              b.x * b.x + b.y * b.y + b.z * b.z + b.w * b.w;
#pragma unroll
    for (int m = 1; m < 64; m <<= 1) s += __shfl_xor(s, m, 64);
    const float rn = rsqrtf(s);
    const float y[8] = {a.x * rn, a.y * rn, a.z * rn, a.w * rn,
                        b.x * rn, b.y * rn, b.z * rn, b.w * rn};
    unsigned int hv[4], lv[4];
#pragma unroll
    for (int i = 0; i < 4; ++i) {
        const unsigned short h0 = f2bf(y[2 * i]);
        const unsigned short h1 = f2bf(y[2 * i + 1]);
        const unsigned short l0 = f2bf(y[2 * i] - bf2f(h0));
        const unsigned short l1 = f2bf(y[2 * i + 1] - bf2f(h1));
        hv[i] = (unsigned int)h0 | ((unsigned int)h1 << 16);
        lv[i] = (unsigned int)l0 | ((unsigned int)l1 << 16);
    }
    uint4* dh = (uint4*)(hi + (size_t)row * DDIM + lane * 8);
    uint4* dl = (uint4*)(lo + (size_t)row * DDIM + lane * 8);
    *dh = make_uint4(hv[0], hv[1], hv[2], hv[3]);
    *dl = make_uint4(lv[0], lv[1], lv[2], lv[3]);
}

// one 128x128 similarity tile: K-loop (co-staged, BK=32, hi/lo 3-pass),
// row/col max/min/argmax/argmin, Zref sums, partial writes. Identical to
// the round-0/round-7 verified k_simstats body (34.5% MfmaUtil optimum).
__device__ __forceinline__ void simstats_tile(
    const unsigned short* __restrict__ ghi, const unsigned short* __restrict__ glo,
    float* __restrict__ pmax, float* __restrict__ pmin, float* __restrict__ pZ,
    int* __restrict__ pamax, int* __restrict__ pamin,
    unsigned short* SH, int I, int J, int t) {
    unsigned short* Ahi = SH;
    unsigned short* Alo = SH + 4096;
    unsigned short* Bhi = SH + 8192;
    unsigned short* Blo = SH + 12288;
    const int wave = t >> 6;
    const int lane = t & 63;
    const int lanelo = lane & 15;
    const int quad = lane >> 4;
    const int wr = wave & 1;
    const int wc = wave >> 1;

    const int srow = t >> 2;                             // 0..63
    const int scolb = ((t & 3) ^ ((t >> 3) & 3)) << 4;   // swizzled src chunk
    char* lAh = (char*)Ahi + t * 16;
    char* lAl = (char*)Alo + t * 16;
    char* lBh = (char*)Bhi + t * 16;
    char* lBl = (char*)Blo + t * 16;

    const int fsl = (quad ^ ((lanelo >> 1) & 3)) << 3;
    const int aoff = (wr * 64 + lanelo) * 32 + fsl;
    const int boff = (wc * 64 + lanelo) * 32 + fsl;

    // epilogue LDS overlays (A half: row stats; B half: col stats)
    float* rm  = (float*)SH;            // [2 wc][128]
    float* rz  = rm + 256;
    float* rmn = rz + 256;
    int*   ra  = (int*)(rmn + 256);
    int*   ran = ra + 256;
    float* cm  = (float*)Bhi;           // [2 wr][128]
    float* cz  = cm + 256;
    float* cmn = cz + 256;
    int*   ca  = (int*)(cmn + 256);
    int*   can = ca + 256;

    const int i0 = I * BM;
    const int j0 = J * BM;
    const bool isdiag = (I == J);

    f32x4 acc[4][4];
#pragma unroll
    for (int rt = 0; rt < 4; ++rt)
#pragma unroll
        for (int ct = 0; ct < 4; ++ct)
            acc[rt][ct] = (f32x4){0.f, 0.f, 0.f, 0.f};

    const char* baseAh = (const char*)ghi + (size_t)(i0 + srow) * 1024 + scolb;
    const char* baseAl = (const char*)glo + (size_t)(i0 + srow) * 1024 + scolb;
    const char* baseBh = (const char*)ghi + (size_t)(j0 + srow) * 1024 + scolb;
    const char* baseBl = (const char*)glo + (size_t)(j0 + srow) * 1024 + scolb;

    for (int k0 = 0; k0 < DDIM; k0 += 32) {
        __syncthreads();  // prior frag/epilogue LDS reads done
#pragma unroll
        for (int q = 0; q < 2; ++q) {
            const size_t roff = (size_t)q * 64 * 1024 + k0 * 2;
            gld16(baseAh + roff, lAh + q * 4096);
            gld16(baseAl + roff, lAl + q * 4096);
            gld16(baseBh + roff, lBh + q * 4096);
            gld16(baseBl + roff, lBl + q * 4096);
        }
        __syncthreads();  // drains vmcnt: staged data visible
        bf16x8 ah[4], al[4];
#pragma unroll
        for (int rt = 0; rt < 4; ++rt) {
            ah[rt] = *(const bf16x8*)&Ahi[aoff + rt * 512];
            al[rt] = *(const bf16x8*)&Alo[aoff + rt * 512];
        }
#pragma unroll
        for (int ct = 0; ct < 4; ++ct) {
            const bf16x8 bh = *(const bf16x8*)&Bhi[boff + ct * 512];
            const bf16x8 bl = *(const bf16x8*)&Blo[boff + ct * 512];
#pragma unroll
            for (int rt = 0; rt < 4; ++rt) {
                acc[rt][ct] = __builtin_amdgcn_mfma_f32_16x16x32_bf16(
                    ah[rt], bh, acc[rt][ct], 0, 0, 0);
                acc[rt][ct] = __builtin_amdgcn_mfma_f32_16x16x32_bf16(
                    ah[rt], bl, acc[rt][ct], 0, 0, 0);
                acc[rt][ct] = __builtin_amdgcn_mfma_f32_16x16x32_bf16(
                    al[rt], bh, acc[rt][ct], 0, 0, 0);
            }
        }
    }

    __syncthreads();  // all frag reads done before LDS overlay

    // phase 1: row max/min (C/D layout: col = lanelo, row = quad*4+reg [m89])
#pragma unroll
    for (int rt = 0; rt < 4; ++rt) {
#pragma unroll
        for (int r = 0; r < 4; ++r) {
            const int lrow = wr * 64 + rt * 16 + quad * 4 + r;
            float tmax = NEGF; int targ = 0;
            float tmin = POSF; int targn = 0;
            if (isdiag) {
                const int gi = i0 + lrow;
#pragma unroll
                for (int ct = 0; ct < 4; ++ct) {
                    const int gj = j0 + wc * 64 + ct * 16 + lanelo;
                    const float v = acc[rt][ct][r];
                    const bool dg = (gj == gi);
                    const float vM = dg ? NEGF : v;
                    const float vm = dg ? POSF : v;
                    if (vM > tmax) { tmax = vM; targ = gj; }  // ct asc = j asc
                    if (vm < tmin) { tmin = vm; targn = gj; }
                }
            } else {
#pragma unroll
                for (int ct = 0; ct < 4; ++ct) {
                    const int gj = j0 + wc * 64 + ct * 16 + lanelo;
                    const float v = acc[rt][ct][r];
                    if (v > tmax) { tmax = v; targ = gj; }
                    if (v < tmin) { tmin = v; targn = gj; }
                }
            }
#pragma unroll
            for (int msk = 1; msk < 16; msk <<= 1) {
                const float v2 = __shfl_xor(tmax, msk, 64);
                const int i2 = __shfl_xor(targ, msk, 64);
                if (v2 > tmax) { tmax = v2; targ = i2; }
                const float v3 = __shfl_xor(tmin, msk, 64);
                const int i3 = __shfl_xor(targn, msk, 64);
                if (v3 < tmin) { tmin = v3; targn = i3; }
            }
            if (lanelo == 0) {
                const int o = wc * 128 + lrow;
                rm[o] = tmax; rmn[o] = tmin;
                ra[o] = targ; ran[o] = targn;
            }
        }
    }

    // phase 2: col max/min (strict-upper only)
    if (!isdiag) {
#pragma unroll
        for (int ct = 0; ct < 4; ++ct) {
            const int lcol = wc * 64 + ct * 16 + lanelo;
            float tmax = NEGF; int targ = 0;
            float tmin = POSF; int targn = 0;
#pragma unroll
            for (int rt = 0; rt < 4; ++rt)
#pragma unroll
                for (int r = 0; r < 4; ++r) {
                    const int gi = i0 + wr * 64 + rt * 16 + quad * 4 + r;
                    const float v = acc[rt][ct][r];
                    if (v > tmax) { tmax = v; targ = gi; }  // gi asc in (rt,r)
                    if (v < tmin) { tmin = v; targn = gi; }
                }
#pragma unroll
            for (int msk = 16; msk < 64; msk <<= 1) {
                const float m2 = __shfl_xor(tmax, msk, 64);
                const int i2 = __shfl_xor(targ, msk, 64);
                if (m2 > tmax) { tmax = m2; targ = i2; }
                const float mn2 = __shfl_xor(tmin, msk, 64);
                const int in2 = __shfl_xor(targn, msk, 64);
                if (mn2 < tmin) { tmin = mn2; targn = in2; }
            }
            if (quad == 0) {
                const int o = wr * 128 + lcol;
                cm[o] = tmax; cmn[o] = tmin;
                ca[o] = targ; can[o] = targn;
            }
        }
    }

    // phase 3: acc <- exp(S-1); zero the 16 diag entries
#pragma unroll
    for (int rt = 0; rt < 4; ++rt)
#pragma unroll
        for (int ct = 0; ct < 4; ++ct)
#pragma unroll
            for (int r = 0; r < 4; ++r)
                acc[rt][ct][r] = __expf(acc[rt][ct][r] - 1.f);
    if (isdiag && wr == wc) {
#pragma unroll
        for (int rt = 0; rt < 4; ++rt)
#pragma unroll
            for (int r = 0; r < 4; ++r)
                if (lanelo == quad * 4 + r) acc[rt][rt][r] = 0.f;
    }

    // phase 4: row Zref sums
#pragma unroll
    for (int rt = 0; rt < 4; ++rt)
#pragma unroll
        for (int r = 0; r < 4; ++r) {
            float s = acc[rt][0][r] + acc[rt][1][r] +
                      acc[rt][2][r] + acc[rt][3][r];
#pragma unroll
            for (int msk = 1; msk < 16; msk <<= 1) s += __shfl_xor(s, msk, 64);
            if (lanelo == 0)
                rz[wc * 128 + wr * 64 + rt * 16 + quad * 4 + r] = s;
        }

    // phase 5: col Zref sums (strict-upper only)
    if (!isdiag) {
#pragma unroll
        for (int ct = 0; ct < 4; ++ct) {
            float s = 0.f;
#pragma unroll
            for (int rt = 0; rt < 4; ++rt)
                s += acc[rt][ct][0] + acc[rt][ct][1] +
                     acc[rt][ct][2] + acc[rt][ct][3];
#pragma unroll
            for (int msk = 16; msk < 64; msk <<= 1) s += __shfl_xor(s, msk, 64);
            if (quad == 0)
                cz[wr * 128 + wc * 64 + ct * 16 + lanelo] = s;
        }
    }

    __syncthreads();

    if (t < BM) {
        // merge row-stat wc-halves (wc0 cols < wc1): row i0+t, slot J
        const float m0 = rm[t], m1 = rm[128 + t];
        float vmax = m0; int imax = ra[t];
        if (m1 > vmax) { vmax = m1; imax = ra[128 + t]; }
        float vmin = rmn[t]; int imin = ran[t];
        if (rmn[128 + t] < vmin) { vmin = rmn[128 + t]; imin = ran[128 + t]; }
        const size_t o = (size_t)J * CDIM + i0 + t;
        pmax[o] = vmax; pmin[o] = vmin; pZ[o] = rz[t] + rz[128 + t];
        pamax[o] = imax; pamin[o] = imin;
    } else if (!isdiag) {
        // merge col-stat wr-halves (wr0 rows < wr1): row j0+tt, slot I
        const int tt = t - BM;
        const float m0 = cm[tt], m1 = cm[128 + tt];
        float vmax = m0; int imax = ca[tt];
        if (m1 > vmax) { vmax = m1; imax = ca[128 + tt]; }
        float vmin = cmn[tt]; int imin = can[tt];
        if (cmn[128 + tt] < vmin) { vmin = cmn[128 + tt]; imin = can[128 + tt]; }
        const size_t o = (size_t)I * CDIM + j0 + tt;
        pmax[o] = vmax; pmin[o] = vmin; pZ[o] = cz[tt] + cz[128 + tt];
        pamax[o] = imax; pamin[o] = imin;
    }
}

// merge 64 slot-partials + triplet distance for one row (one wave).
__device__ __forceinline__ void lossc_row(
    const float* __restrict__ pmax, const float* __restrict__ pmin,
    const float* __restrict__ pZ, const int* __restrict__ pamax,
    const int* __restrict__ pamin, const float* __restrict__ w,
    float* __restrict__ vals, int row, int lane) {
    const size_t o = (size_t)lane * CDIM + row;
    float v = pmax[o]; int a = pamax[o];
    float u = pmin[o]; int b = pamin[o];
    float z = pZ[o];
#pragma unroll
    for (int msk = 1; msk < 64; msk <<= 1) {
        const float v2 = __shfl_xor(v, msk, 64);
        const int i2 = __shfl_xor(a, msk, 64);
        if (v2 > v) { v = v2; a = i2; }
        const float v3 = __shfl_xor(u, msk, 64);
        const int i3 = __shfl_xor(b, msk, 64);
        if (v3 < u) { u = v3; b = i3; }
        z += __shfl_xor(z, msk, 64);
    }
    // P[ms]-P[ls] = (1 - exp(mn-M)) * exp(M-1) / Zref
    const float margin = (1.f - __expf(u - v)) * __expf(v - 1.f) / z;
    const int jm = a, jl = b;

    const float4* wi = (const float4*)(w + (size_t)row * DDIM);
    const float4* wm = (const float4*)(w + (size_t)jm * DDIM);
    const float4* wl = (const float4*)(w + (size_t)jl * DDIM);
    float sm = 0.f, sl = 0.f;
#pragma unroll
    for (int h = 0; h < 2; ++h) {
        const int idx = h * 64 + lane;
        const float4 x = wi[idx];
        const float4 y = wm[idx];
        const float4 c = wl[idx];
        float d;
        d = x.x - y.x; sm = fmaf(d, d, sm);
        d = x.y - y.y; sm = fmaf(d, d, sm);
        d = x.z - y.z; sm = fmaf(d, d, sm);
        d = x.w - y.w; sm = fmaf(d, d, sm);
        d = x.x - c.x; sl = fmaf(d, d, sl);
        d = x.y - c.y; sl = fmaf(d, d, sl);
        d = x.z - c.z; sl = fmaf(d, d, sl);
        d = x.w - c.w; sl = fmaf(d, d, sl);
    }
#pragma unroll
    for (int msk = 1; msk < 64; msk <<= 1) {
        sm += __shfl_xor(sm, msk, 64);
        sl += __shfl_xor(sl, msk, 64);
    }
    if (lane == 0) {
        const float val = sqrtf(sm) - sqrtf(sl) + margin;
        vals[row] = val > 0.f ? val : 0.f;
    }
}

// deterministic fixed-order mean (EXACT association of the original
// k_final: per-thread strided sum then 256-tree). red = 256 floats.
__device__ __forceinline__ void final_mean(const float* __restrict__ vals,
                                           float* __restrict__ out,
                                           float* red, int t) {
    float s = 0.f;
    for (int i = t; i < CDIM; i += 256) s += vals[i];
    red[t] = s;
    __syncthreads();
#pragma unroll
    for (int k = 128; k > 0; k >>= 1) {
        if (t < k) red[t] += red[t + k];
        __syncthreads();
    }
    if (t == 0) out[0] = red[0] * (1.0f / CDIM);
}

// ============ fused single-dispatch cooperative kernel ============
// Round-8: across all rounds, total - k_simstats ~= 95-99 us while the
// three small kernels model to ~20-35 us -> ~60-75 us is inter-dispatch
// overhead (4 serialized launches). Fuse all phases into ONE cooperative
// launch: grid 768 = 3 blocks/CU co-resident (round-0's proven simstats
// occupancy), grid.sync() between phases (+ threadfence for cross-XCD
// visibility). The S phase keeps round-0's dynamic balance AND XCD-L2
// supertile locality via 8 per-XCD atomic tile queues (block on XCD
// bid&7 pops off = atomicAdd(ctr[xcd]) -> same (xcd,off)->(I,J) map).
// All phase bodies are the shared device functions above -> numerics
// bit-identical to the verified 4-kernel path (absmax 0.0 preserved).
__global__ __launch_bounds__(256, 3) void k_fused(
    const float* __restrict__ g, const float* __restrict__ w,
    unsigned short* __restrict__ ghi, unsigned short* __restrict__ glo,
    float* __restrict__ pmax, float* __restrict__ pmin, float* __restrict__ pZ,
    int* __restrict__ pamax, int* __restrict__ pamin,
    float* __restrict__ vals, int* __restrict__ ctr, float* __restrict__ out) {
    __shared__ unsigned short SH[4 * BM * 32];  // 32 KB (tile + overlays)
    __shared__ int s_off;
    const int t = threadIdx.x;
    const int wave = t >> 6;
    const int lane = t & 63;
    const int bid = blockIdx.x;
    const int xcd = bid & 7;
    const int wglob = bid * 4 + wave;  // 0..3071

    // ---- phase P: prep (3072 waves x <=3 rows) + zero tile queues ----
    if (bid == 0 && t < 8) ctr[t] = 0;
#pragma unroll
    for (int j = 0; j < 3; ++j) {
        const int row = wglob + 3072 * j;   // wave-uniform guard
        if (row < CDIM) prep_row(g, ghi, glo, row, lane);
    }
    __threadfence();
    cg::this_grid().sync();

    // ---- phase S: similarity tiles, per-XCD dynamic queues ----
    const int lim = (xcd < 4) ? 264 : 256;
    while (true) {
        __syncthreads();   // protect s_off reuse + prior tile's LDS reads
        if (t == 0) s_off = atomicAdd(&ctr[xcd], 1);
        __syncthreads();
        const int off = s_off;          // block-uniform
        if (off >= lim) break;
        int I, J;
        tile_map(xcd, off, I, J);
        simstats_tile(ghi, glo, pmax, pmin, pZ, pamax, pamin, SH, I, J, t);
    }
    __threadfence();
    cg::this_grid().sync();

    // ---- phase L: loss rows (3072 waves x <=3 rows) ----
#pragma unroll
    for (int j = 0; j < 3; ++j) {
        const int row = wglob + 3072 * j;
        if (row < CDIM) lossc_row(pmax, pmin, pZ, pamax, pamin, w, vals, row, lane);
    }
    __threadfence();
    cg::this_grid().sync();

    // ---- phase F: block 0 runs the exact k_final body ----
    if (bid == 0) final_mean(vals, out, (float*)SH, t);
}

// ============ fallback 4-kernel path (proven 229 us) ============

__global__ __launch_bounds__(256) void k_prep(const float* __restrict__ g,
                                              unsigned short* __restrict__ hi,
                                              unsigned short* __restrict__ lo) {
    const int wave = threadIdx.x >> 6;
    const int lane = threadIdx.x & 63;
    prep_row(g, hi, lo, blockIdx.x * 4 + wave, lane);
}

__global__ __launch_bounds__(256, 3) void k_simstats(
    const unsigned short* __restrict__ ghi, const unsigned short* __restrict__ glo,
    float* __restrict__ pmax, float* __restrict__ pmin, float* __restrict__ pZ,
    int* __restrict__ pamax, int* __restrict__ pamin) {
    __shared__ unsigned short SH[4 * BM * 32];
    const int bid = blockIdx.x;
    const int xcd = bid & 7;
    const int off = bid >> 3;
    if (xcd >= 4 && off >= 256) return;  // 32 pad blocks
    int I, J;
    tile_map(xcd, off, I, J);
    simstats_tile(ghi, glo, pmax, pmin, pZ, pamax, pamin, SH, I, J,
                  (int)threadIdx.x);
}

__global__ __launch_bounds__(256) void k_lossc(
    const float* __restrict__ pmax, const float* __restrict__ pmin,
    const float* __restrict__ pZ, const int* __restrict__ pamax,
    const int* __restrict__ pamin, const float* __restrict__ w,
    float* __restrict__ vals) {
    const int wave = threadIdx.x >> 6;
    const int lane = threadIdx.x & 63;
    lossc_row(pmax, pmin, pZ, pamax, pamin, w, vals, blockIdx.x * 4 + wave, lane);
}

__global__ __launch_bounds__(256) void k_final(const float* __restrict__ vals,
                                               float* __restrict__ out) {
    __shared__ float red[256];
    final_mean(vals, out, red, (int)threadIdx.x);
}

extern "C" void kernel_launch(void* const* d_in, const int* in_sizes, int n_in,
                              void* d_out, int out_size, void* d_ws, size_t ws_size,
                              hipStream_t stream) {
    const float* g = (const float*)d_in[0];  // gt_class_embeddings [8192,512]
    const float* w = (const float*)d_in[1];  // w [8192,512]
    float* out = (float*)d_out;

    // workspace layout (~26.6 MB + 32 B queue counters)
    unsigned short* ghi = (unsigned short*)d_ws;
    unsigned short* glo = ghi + (size_t)CDIM * DDIM;
    float* p = (float*)(glo + (size_t)CDIM * DDIM);
    float* pmax = p;      p += (size_t)NSLOT * CDIM;
    float* pmin = p;      p += (size_t)NSLOT * CDIM;
    float* pZ = p;        p += (size_t)NSLOT * CDIM;
    int* pamax = (int*)p; p += (size_t)NSLOT * CDIM;
    int* pamin = (int*)p; p += (size_t)NSLOT * CDIM;
    float* vals = p;      p += CDIM;
    int* ctr = (int*)p;   // 8 ints, zeroed in-kernel each launch

    void* args[12];
    args[0] = (void*)&g;     args[1] = (void*)&w;
    args[2] = (void*)&ghi;   args[3] = (void*)&glo;
    args[4] = (void*)&pmax;  args[5] = (void*)&pmin;
    args[6] = (void*)&pZ;    args[7] = (void*)&pamax;
    args[8] = (void*)&pamin; args[9] = (void*)&vals;
    args[10] = (void*)&ctr;  args[11] = (void*)&out;

    if (hipLaunchCooperativeKernel((const void*)k_fused, dim3(768), dim3(256),
                                   args, 0, stream) != hipSuccess) {
        // fallback: proven 4-kernel path (229 us)
        k_prep<<<CDIM / 4, 256, 0, stream>>>(g, ghi, glo);
        k_simstats<<<2112, 256, 0, stream>>>(ghi, glo, pmax, pmin, pZ,
                                             pamax, pamin);
        k_lossc<<<CDIM / 4, 256, 0, stream>>>(pmax, pmin, pZ, pamax, pamin,
                                              w, vals);
        k_final<<<1, 256, 0, stream>>>(vals, out);
    }
}

// Round 9
// 415.852 us; speedup vs baseline: 1.5901x; 1.5901x over previous
//
#include <hip/hip_runtime.h>
#include <math.h>

#define CDIM 8192
#define DDIM 512
#define NEGF -3.0e38f
#define POSF  3.0e38f

#define BM 128
#define NSLOT (CDIM / BM) /* 64 col-slots of 128 per row */

typedef __attribute__((ext_vector_type(8))) short bf16x8;
typedef __attribute__((ext_vector_type(4))) float f32x4;

__device__ __forceinline__ unsigned short f2bf(float x) {
    unsigned int u = __float_as_uint(x);
    u += 0x7fffu + ((u >> 16) & 1u);
    return (unsigned short)(u >> 16);
}
__device__ __forceinline__ float bf2f(unsigned short h) {
    return __uint_as_float(((unsigned int)h) << 16);
}
// async global->LDS, 16B per lane. LDS dest is wave-uniform base + lane*16.
__device__ __forceinline__ void gld16(const void* g, void* l) {
    __builtin_amdgcn_global_load_lds(
        (__attribute__((address_space(1))) void*)(void*)g,
        (__attribute__((address_space(3))) void*)l, 16, 0, 0);
}

// Off-diag super-tile assignment table: code = SI*8+SJ (SI<SJ, 8x8 super
// grid over the 64x64 tile grid). XCD0-3: 3 supers each; XCD4-7: 4 supers
// each. XCD0-3 also carry 2 diagonal supers -> 264 tiles; XCD4-7: 256.
__device__ __constant__ unsigned char OSUP[28] = {
    1, 2, 10,   3, 11, 19,   4, 12, 20,   28, 5, 13,
    21, 29, 37, 6,   14, 22, 30, 38,   46, 7, 15, 23,   31, 39, 47, 55};

// (xcd, off) -> tile (I,J). off must be < 264 (xcd<4) / 256 (xcd>=4).
__device__ __forceinline__ void tile_map(int xcd, int off, int& I, int& J) {
    if (xcd < 4) {
        if (off < 72) {  // two diagonal supers: s = xcd*2 + (off>=36)
            const int s = xcd * 2 + (off >= 36);
            const int u = (off >= 36) ? off - 36 : off;
            int jj = 0;  // triangular: i<=j within the 8x8 super, i fastest
            while ((jj + 1) * (jj + 2) / 2 <= u) ++jj;
            const int ii = u - jj * (jj + 1) / 2;
            I = s * 8 + ii; J = s * 8 + jj;
        } else {
            const int sup = (off - 72) >> 6;
            const int u = (off - 72) & 63;
            const int code = OSUP[xcd * 3 + sup];
            I = (code >> 3) * 8 + (u & 7);   // I fastest: B-tile shared x8
            J = (code & 7) * 8 + (u >> 3);
        }
    } else {
        const int sup = off >> 6;
        const int u = off & 63;
        const int code = OSUP[12 + (xcd - 4) * 4 + sup];
        I = (code >> 3) * 8 + (u & 7);
        J = (code & 7) * 8 + (u >> 3);
    }
}

// ============ shared device bodies (verified rounds 0-8, bit-identical) ====

// normalize row of G, split into bf16 hi/lo. All 64 lanes of a wave call.
__device__ __forceinline__ void prep_row(const float* __restrict__ g,
                                         unsigned short* __restrict__ hi,
                                         unsigned short* __restrict__ lo,
                                         int row, int lane) {
    const float4* src = (const float4*)(g + (size_t)row * DDIM);
    const float4 a = src[lane * 2];
    const float4 b = src[lane * 2 + 1];
    float s = a.x * a.x + a.y * a.y + a.z * a.z + a.w * a.w +
              b.x * b.x + b.y * b.y + b.z * b.z + b.w * b.w;
#pragma unroll
    for (int m = 1; m < 64; m <<= 1) s += __shfl_xor(s, m, 64);
    const float rn = rsqrtf(s);
    const float y[8] = {a.x * rn, a.y * rn, a.z * rn, a.w * rn,
                        b.x * rn, b.y * rn, b.z * rn, b.w * rn};
    unsigned int hv[4], lv[4];
#pragma unroll
    for (int i = 0; i < 4; ++i) {
        const unsigned short h0 = f2bf(y[2 * i]);
        const unsigned short h1 = f2bf(y[2 * i + 1]);
        const unsigned short l0 = f2bf(y[2 * i] - bf2f(h0));
        const unsigned short l1 = f2bf(y[2 * i + 1] - bf2f(h1));
        hv[i] = (unsigned int)h0 | ((unsigned int)h1 << 16);
        lv[i] = (unsigned int)l0 | ((unsigned int)l1 << 16);
    }
    uint4* dh = (uint4*)(hi + (size_t)row * DDIM + lane * 8);
    uint4* dl = (uint4*)(lo + (size_t)row * DDIM + lane * 8);
    *dh = make_uint4(hv[0], hv[1], hv[2], hv[3]);
    *dl = make_uint4(lv[0], lv[1], lv[2], lv[3]);
}

// one 128x128 similarity tile (round-0 verified optimum: 34.5% MfmaUtil).
__device__ __forceinline__ void simstats_tile(
    const unsigned short* __restrict__ ghi, const unsigned short* __restrict__ glo,
    float* __restrict__ pmax, float* __restrict__ pmin, float* __restrict__ pZ,
    int* __restrict__ pamax, int* __restrict__ pamin,
    unsigned short* SH, int I, int J, int t) {
    unsigned short* Ahi = SH;
    unsigned short* Alo = SH + 4096;
    unsigned short* Bhi = SH + 8192;
    unsigned short* Blo = SH + 12288;
    const int wave = t >> 6;
    const int lane = t & 63;
    const int lanelo = lane & 15;
    const int quad = lane >> 4;
    const int wr = wave & 1;
    const int wc = wave >> 1;

    const int srow = t >> 2;                             // 0..63
    const int scolb = ((t & 3) ^ ((t >> 3) & 3)) << 4;   // swizzled src chunk
    char* lAh = (char*)Ahi + t * 16;
    char* lAl = (char*)Alo + t * 16;
    char* lBh = (char*)Bhi + t * 16;
    char* lBl = (char*)Blo + t * 16;

    const int fsl = (quad ^ ((lanelo >> 1) & 3)) << 3;
    const int aoff = (wr * 64 + lanelo) * 32 + fsl;
    const int boff = (wc * 64 + lanelo) * 32 + fsl;

    // epilogue LDS overlays (A half: row stats; B half: col stats)
    float* rm  = (float*)SH;            // [2 wc][128]
    float* rz  = rm + 256;
    float* rmn = rz + 256;
    int*   ra  = (int*)(rmn + 256);
    int*   ran = ra + 256;
    float* cm  = (float*)Bhi;           // [2 wr][128]
    float* cz  = cm + 256;
    float* cmn = cz + 256;
    int*   ca  = (int*)(cmn + 256);
    int*   can = ca + 256;

    const int i0 = I * BM;
    const int j0 = J * BM;
    const bool isdiag = (I == J);

    f32x4 acc[4][4];
#pragma unroll
    for (int rt = 0; rt < 4; ++rt)
#pragma unroll
        for (int ct = 0; ct < 4; ++ct)
            acc[rt][ct] = (f32x4){0.f, 0.f, 0.f, 0.f};

    const char* baseAh = (const char*)ghi + (size_t)(i0 + srow) * 1024 + scolb;
    const char* baseAl = (const char*)glo + (size_t)(i0 + srow) * 1024 + scolb;
    const char* baseBh = (const char*)ghi + (size_t)(j0 + srow) * 1024 + scolb;
    const char* baseBl = (const char*)glo + (size_t)(j0 + srow) * 1024 + scolb;

    for (int k0 = 0; k0 < DDIM; k0 += 32) {
        __syncthreads();  // prior frag/epilogue LDS reads done
#pragma unroll
        for (int q = 0; q < 2; ++q) {
            const size_t roff = (size_t)q * 64 * 1024 + k0 * 2;
            gld16(baseAh + roff, lAh + q * 4096);
            gld16(baseAl + roff, lAl + q * 4096);
            gld16(baseBh + roff, lBh + q * 4096);
            gld16(baseBl + roff, lBl + q * 4096);
        }
        __syncthreads();  // drains vmcnt: staged data visible
        bf16x8 ah[4], al[4];
#pragma unroll
        for (int rt = 0; rt < 4; ++rt) {
            ah[rt] = *(const bf16x8*)&Ahi[aoff + rt * 512];
            al[rt] = *(const bf16x8*)&Alo[aoff + rt * 512];
        }
#pragma unroll
        for (int ct = 0; ct < 4; ++ct) {
            const bf16x8 bh = *(const bf16x8*)&Bhi[boff + ct * 512];
            const bf16x8 bl = *(const bf16x8*)&Blo[boff + ct * 512];
#pragma unroll
            for (int rt = 0; rt < 4; ++rt) {
                acc[rt][ct] = __builtin_amdgcn_mfma_f32_16x16x32_bf16(
                    ah[rt], bh, acc[rt][ct], 0, 0, 0);
                acc[rt][ct] = __builtin_amdgcn_mfma_f32_16x16x32_bf16(
                    ah[rt], bl, acc[rt][ct], 0, 0, 0);
                acc[rt][ct] = __builtin_amdgcn_mfma_f32_16x16x32_bf16(
                    al[rt], bh, acc[rt][ct], 0, 0, 0);
            }
        }
    }

    __syncthreads();  // all frag reads done before LDS overlay

    // phase 1: row max/min (C/D layout: col = lanelo, row = quad*4+reg [m89])
#pragma unroll
    for (int rt = 0; rt < 4; ++rt) {
#pragma unroll
        for (int r = 0; r < 4; ++r) {
            const int lrow = wr * 64 + rt * 16 + quad * 4 + r;
            float tmax = NEGF; int targ = 0;
            float tmin = POSF; int targn = 0;
            if (isdiag) {
                const int gi = i0 + lrow;
#pragma unroll
                for (int ct = 0; ct < 4; ++ct) {
                    const int gj = j0 + wc * 64 + ct * 16 + lanelo;
                    const float v = acc[rt][ct][r];
                    const bool dg = (gj == gi);
                    const float vM = dg ? NEGF : v;
                    const float vm = dg ? POSF : v;
                    if (vM > tmax) { tmax = vM; targ = gj; }  // ct asc = j asc
                    if (vm < tmin) { tmin = vm; targn = gj; }
                }
            } else {
#pragma unroll
                for (int ct = 0; ct < 4; ++ct) {
                    const int gj = j0 + wc * 64 + ct * 16 + lanelo;
                    const float v = acc[rt][ct][r];
                    if (v > tmax) { tmax = v; targ = gj; }
                    if (v < tmin) { tmin = v; targn = gj; }
                }
            }
#pragma unroll
            for (int msk = 1; msk < 16; msk <<= 1) {
                const float v2 = __shfl_xor(tmax, msk, 64);
                const int i2 = __shfl_xor(targ, msk, 64);
                if (v2 > tmax) { tmax = v2; targ = i2; }
                const float v3 = __shfl_xor(tmin, msk, 64);
                const int i3 = __shfl_xor(targn, msk, 64);
                if (v3 < tmin) { tmin = v3; targn = i3; }
            }
            if (lanelo == 0) {
                const int o = wc * 128 + lrow;
                rm[o] = tmax; rmn[o] = tmin;
                ra[o] = targ; ran[o] = targn;
            }
        }
    }

    // phase 2: col max/min (strict-upper only)
    if (!isdiag) {
#pragma unroll
        for (int ct = 0; ct < 4; ++ct) {
            const int lcol = wc * 64 + ct * 16 + lanelo;
            float tmax = NEGF; int targ = 0;
            float tmin = POSF; int targn = 0;
#pragma unroll
            for (int rt = 0; rt < 4; ++rt)
#pragma unroll
                for (int r = 0; r < 4; ++r) {
                    const int gi = i0 + wr * 64 + rt * 16 + quad * 4 + r;
                    const float v = acc[rt][ct][r];
                    if (v > tmax) { tmax = v; targ = gi; }  // gi asc in (rt,r)
                    if (v < tmin) { tmin = v; targn = gi; }
                }
#pragma unroll
            for (int msk = 16; msk < 64; msk <<= 1) {
                const float m2 = __shfl_xor(tmax, msk, 64);
                const int i2 = __shfl_xor(targ, msk, 64);
                if (m2 > tmax) { tmax = m2; targ = i2; }
                const float mn2 = __shfl_xor(tmin, msk, 64);
                const int in2 = __shfl_xor(targn, msk, 64);
                if (mn2 < tmin) { tmin = mn2; targn = in2; }
            }
            if (quad == 0) {
                const int o = wr * 128 + lcol;
                cm[o] = tmax; cmn[o] = tmin;
                ca[o] = targ; can[o] = targn;
            }
        }
    }

    // phase 3: acc <- exp(S-1); zero the 16 diag entries
#pragma unroll
    for (int rt = 0; rt < 4; ++rt)
#pragma unroll
        for (int ct = 0; ct < 4; ++ct)
#pragma unroll
            for (int r = 0; r < 4; ++r)
                acc[rt][ct][r] = __expf(acc[rt][ct][r] - 1.f);
    if (isdiag && wr == wc) {
#pragma unroll
        for (int rt = 0; rt < 4; ++rt)
#pragma unroll
            for (int r = 0; r < 4; ++r)
                if (lanelo == quad * 4 + r) acc[rt][rt][r] = 0.f;
    }

    // phase 4: row Zref sums
#pragma unroll
    for (int rt = 0; rt < 4; ++rt)
#pragma unroll
        for (int r = 0; r < 4; ++r) {
            float s = acc[rt][0][r] + acc[rt][1][r] +
                      acc[rt][2][r] + acc[rt][3][r];
#pragma unroll
            for (int msk = 1; msk < 16; msk <<= 1) s += __shfl_xor(s, msk, 64);
            if (lanelo == 0)
                rz[wc * 128 + wr * 64 + rt * 16 + quad * 4 + r] = s;
        }

    // phase 5: col Zref sums (strict-upper only)
    if (!isdiag) {
#pragma unroll
        for (int ct = 0; ct < 4; ++ct) {
            float s = 0.f;
#pragma unroll
            for (int rt = 0; rt < 4; ++rt)
                s += acc[rt][ct][0] + acc[rt][ct][1] +
                     acc[rt][ct][2] + acc[rt][ct][3];
#pragma unroll
            for (int msk = 16; msk < 64; msk <<= 1) s += __shfl_xor(s, msk, 64);
            if (quad == 0)
                cz[wr * 128 + wc * 64 + ct * 16 + lanelo] = s;
        }
    }

    __syncthreads();

    if (t < BM) {
        // merge row-stat wc-halves (wc0 cols < wc1): row i0+t, slot J
        const float m0 = rm[t], m1 = rm[128 + t];
        float vmax = m0; int imax = ra[t];
        if (m1 > vmax) { vmax = m1; imax = ra[128 + t]; }
        float vmin = rmn[t]; int imin = ran[t];
        if (rmn[128 + t] < vmin) { vmin = rmn[128 + t]; imin = ran[128 + t]; }
        const size_t o = (size_t)J * CDIM + i0 + t;
        pmax[o] = vmax; pmin[o] = vmin; pZ[o] = rz[t] + rz[128 + t];
        pamax[o] = imax; pamin[o] = imin;
    } else if (!isdiag) {
        // merge col-stat wr-halves (wr0 rows < wr1): row j0+tt, slot I
        const int tt = t - BM;
        const float m0 = cm[tt], m1 = cm[128 + tt];
        float vmax = m0; int imax = ca[tt];
        if (m1 > vmax) { vmax = m1; imax = ca[128 + tt]; }
        float vmin = cmn[tt]; int imin = can[tt];
        if (cmn[128 + tt] < vmin) { vmin = cmn[128 + tt]; imin = can[128 + tt]; }
        const size_t o = (size_t)I * CDIM + j0 + tt;
        pmax[o] = vmax; pmin[o] = vmin; pZ[o] = cz[tt] + cz[128 + tt];
        pamax[o] = imax; pamin[o] = imin;
    }
}

// merge 64 slot-partials + triplet distance for one row (one wave).
__device__ __forceinline__ void lossc_row(
    const float* __restrict__ pmax, const float* __restrict__ pmin,
    const float* __restrict__ pZ, const int* __restrict__ pamax,
    const int* __restrict__ pamin, const float* __restrict__ w,
    float* __restrict__ vals, int row, int lane) {
    const size_t o = (size_t)lane * CDIM + row;
    float v = pmax[o]; int a = pamax[o];
    float u = pmin[o]; int b = pamin[o];
    float z = pZ[o];
#pragma unroll
    for (int msk = 1; msk < 64; msk <<= 1) {
        const float v2 = __shfl_xor(v, msk, 64);
        const int i2 = __shfl_xor(a, msk, 64);
        if (v2 > v) { v = v2; a = i2; }
        const float v3 = __shfl_xor(u, msk, 64);
        const int i3 = __shfl_xor(b, msk, 64);
        if (v3 < u) { u = v3; b = i3; }
        z += __shfl_xor(z, msk, 64);
    }
    // P[ms]-P[ls] = (1 - exp(mn-M)) * exp(M-1) / Zref
    const float margin = (1.f - __expf(u - v)) * __expf(v - 1.f) / z;
    const int jm = a, jl = b;

    const float4* wi = (const float4*)(w + (size_t)row * DDIM);
    const float4* wm = (const float4*)(w + (size_t)jm * DDIM);
    const float4* wl = (const float4*)(w + (size_t)jl * DDIM);
    float sm = 0.f, sl = 0.f;
#pragma unroll
    for (int h = 0; h < 2; ++h) {
        const int idx = h * 64 + lane;
        const float4 x = wi[idx];
        const float4 y = wm[idx];
        const float4 c = wl[idx];
        float d;
        d = x.x - y.x; sm = fmaf(d, d, sm);
        d = x.y - y.y; sm = fmaf(d, d, sm);
        d = x.z - y.z; sm = fmaf(d, d, sm);
        d = x.w - y.w; sm = fmaf(d, d, sm);
        d = x.x - c.x; sl = fmaf(d, d, sl);
        d = x.y - c.y; sl = fmaf(d, d, sl);
        d = x.z - c.z; sl = fmaf(d, d, sl);
        d = x.w - c.w; sl = fmaf(d, d, sl);
    }
#pragma unroll
    for (int msk = 1; msk < 64; msk <<= 1) {
        sm += __shfl_xor(sm, msk, 64);
        sl += __shfl_xor(sl, msk, 64);
    }
    if (lane == 0) {
        const float val = sqrtf(sm) - sqrtf(sl) + margin;
        vals[row] = val > 0.f ? val : 0.f;
    }
}

// deterministic fixed-order mean (EXACT association of the original
// k_final: per-thread strided sum then 256-tree). red = 256 floats.
__device__ __forceinline__ void final_mean(const float* __restrict__ vals,
                                           float* __restrict__ out,
                                           float* red, int t) {
    float s = 0.f;
    for (int i = t; i < CDIM; i += 256) s += vals[i];
    red[t] = s;
    __syncthreads();
#pragma unroll
    for (int k = 128; k > 0; k >>= 1) {
        if (t < k) red[t] += red[t + k];
        __syncthreads();
    }
    if (t == 0) out[0] = red[0] * (1.0f / CDIM);
}

// ---- k_prep: 2048 blocks x 4 waves; block 0 also zeroes the counters ----
__global__ __launch_bounds__(256) void k_prep(const float* __restrict__ g,
                                              unsigned short* __restrict__ hi,
                                              unsigned short* __restrict__ lo,
                                              int* __restrict__ ctrz) {
    if (blockIdx.x == 0 && threadIdx.x < 65) ctrz[threadIdx.x] = 0;
    const int wave = threadIdx.x >> 6;
    const int lane = threadIdx.x & 63;
    prep_row(g, hi, lo, blockIdx.x * 4 + wave, lane);
}

// ---- k_simstats: round-7 verified tile body + FUSED band-loss tail ----
// Round-9: grid.sync fusion (R8) refuted (604us, spin-wait storm). This
// round fuses lossc+final via the deadlock-free LAST-CONTRIBUTOR pattern
// (Guideline 16: device-scope atomics + fences; no block ever waits on a
// block that hasn't started). Band b (128 rows) is loss-ready after its
// 64 slot-partials are written = exactly 64 tile contributions (row-stats
// from tiles (b,J>=b): 64-b; col-stats from (I<b,b): b; diag: 1). After a
// block's partial writes: __syncthreads (vmcnt drained -> stores in this
// XCD's L2), thread0 __threadfence (device-scope release: L2 writeback),
// atomicAdd(bandc). The 64th contributor OWNS the band: acquire fence,
// run its 128 lossc rows (4 waves x 32, unroll-2 for MLP), then the same
// pattern on done2 -- the 64th band-owner runs the exact k_final tree.
// Math bit-identical to the 4-kernel path (same lossc_row/final_mean,
// each (slot,row)/val written once, fixed-order reduction). Saves 2 of 3
// launch boundaries; band-loss overlaps remaining tiles except the last
// band (~10-15us tail).
__global__ __launch_bounds__(256, 3) void k_simstats(
    const unsigned short* __restrict__ ghi, const unsigned short* __restrict__ glo,
    float* __restrict__ pmax, float* __restrict__ pmin, float* __restrict__ pZ,
    int* __restrict__ pamax, int* __restrict__ pamin,
    const float* __restrict__ w, float* __restrict__ vals,
    int* __restrict__ bandc, int* __restrict__ done2, float* __restrict__ out) {
    __shared__ unsigned short SH[4 * BM * 32];
    __shared__ int s_ownR, s_ownC, s_fin;
    const int bid = blockIdx.x;
    const int xcd = bid & 7;
    const int off = bid >> 3;
    if (xcd >= 4 && off >= 256) return;  // 32 pad blocks
    int I, J;
    tile_map(xcd, off, I, J);
    const int t = threadIdx.x;
    const int wave = t >> 6;
    const int lane = t & 63;

    simstats_tile(ghi, glo, pmax, pmin, pZ, pamax, pamin, SH, I, J, t);

    // ---- band completion accounting (release) ----
    __syncthreads();   // partial stores retired (barrier drains vmcnt)
    if (t == 0) {
        __threadfence();                                   // flush to device
        s_ownR = (atomicAdd(&bandc[I], 1) + 1 == 64);
        s_ownC = (I != J) && (atomicAdd(&bandc[J], 1) + 1 == 64);
    }
    __syncthreads();

    const int nown = (s_ownR ? 1 : 0) + (s_ownC ? 1 : 0);
    if (nown) {
        __threadfence();   // acquire: no stale partials from other XCDs
        if (s_ownR) {
#pragma unroll 2
            for (int rr = wave; rr < BM; rr += 4)
                lossc_row(pmax, pmin, pZ, pamax, pamin, w, vals,
                          I * BM + rr, lane);
        }
        if (s_ownC) {
#pragma unroll 2
            for (int rr = wave; rr < BM; rr += 4)
                lossc_row(pmax, pmin, pZ, pamax, pamin, w, vals,
                          J * BM + rr, lane);
        }
        __syncthreads();   // this block's vals stores retired
        if (t == 0) {
            __threadfence();                               // release vals
            s_fin = (atomicAdd(done2, nown) + nown == 64);
        }
        __syncthreads();
        if (s_fin) {
            __threadfence();   // acquire vals from other owners
            final_mean(vals, out, (float*)SH, t);
        }
    }
}

extern "C" void kernel_launch(void* const* d_in, const int* in_sizes, int n_in,
                              void* d_out, int out_size, void* d_ws, size_t ws_size,
                              hipStream_t stream) {
    const float* g = (const float*)d_in[0];  // gt_class_embeddings [8192,512]
    const float* w = (const float*)d_in[1];  // w [8192,512]
    float* out = (float*)d_out;

    // workspace layout (~26.6 MB + counters)
    unsigned short* ghi = (unsigned short*)d_ws;
    unsigned short* glo = ghi + (size_t)CDIM * DDIM;
    float* p = (float*)(glo + (size_t)CDIM * DDIM);
    float* pmax = p;      p += (size_t)NSLOT * CDIM;
    float* pmin = p;      p += (size_t)NSLOT * CDIM;
    float* pZ = p;        p += (size_t)NSLOT * CDIM;
    int* pamax = (int*)p; p += (size_t)NSLOT * CDIM;
    int* pamin = (int*)p; p += (size_t)NSLOT * CDIM;
    float* vals = p;      p += CDIM;
    int* bandc = (int*)p; // 64 band counters + done2 (zeroed by k_prep)
    int* done2 = bandc + 64;

    k_prep<<<CDIM / 4, 256, 0, stream>>>(g, ghi, glo, bandc);
    k_simstats<<<2112, 256, 0, stream>>>(ghi, glo, pmax, pmin, pZ, pamax,
                                         pamin, w, vals, bandc, done2, out);
}

// Round 10
// 236.894 us; speedup vs baseline: 2.7913x; 1.7554x over previous
//
#include <hip/hip_runtime.h>
#include <math.h>

#define CDIM 8192
#define DDIM 512
#define NEGF -3.0e38f
#define POSF  3.0e38f

#define BM 128
#define NSLOT (CDIM / BM) /* 64 col-slots of 128 per row */

typedef __attribute__((ext_vector_type(8))) short bf16x8;
typedef __attribute__((ext_vector_type(4))) float f32x4;

__device__ __forceinline__ unsigned short f2bf(float x) {
    unsigned int u = __float_as_uint(x);
    u += 0x7fffu + ((u >> 16) & 1u);
    return (unsigned short)(u >> 16);
}
__device__ __forceinline__ float bf2f(unsigned short h) {
    return __uint_as_float(((unsigned int)h) << 16);
}
// async global->LDS, 16B per lane. LDS dest is wave-uniform base + lane*16.
__device__ __forceinline__ void gld16(const void* g, void* l) {
    __builtin_amdgcn_global_load_lds(
        (__attribute__((address_space(1))) void*)(void*)g,
        (__attribute__((address_space(3))) void*)l, 16, 0, 0);
}

// ---- k_prep: normalize rows of G, split into bf16 hi/lo ----
__global__ __launch_bounds__(256) void k_prep(const float* __restrict__ g,
                                              unsigned short* __restrict__ hi,
                                              unsigned short* __restrict__ lo) {
    const int wave = threadIdx.x >> 6;
    const int lane = threadIdx.x & 63;
    const int row = blockIdx.x * 4 + wave;
    const float4* src = (const float4*)(g + (size_t)row * DDIM);
    const float4 a = src[lane * 2];
    const float4 b = src[lane * 2 + 1];
    float s = a.x * a.x + a.y * a.y + a.z * a.z + a.w * a.w +
              b.x * b.x + b.y * b.y + b.z * b.z + b.w * b.w;
#pragma unroll
    for (int m = 1; m < 64; m <<= 1) s += __shfl_xor(s, m, 64);
    const float rn = rsqrtf(s);
    const float y[8] = {a.x * rn, a.y * rn, a.z * rn, a.w * rn,
                        b.x * rn, b.y * rn, b.z * rn, b.w * rn};
    unsigned int hv[4], lv[4];
#pragma unroll
    for (int i = 0; i < 4; ++i) {
        const unsigned short h0 = f2bf(y[2 * i]);
        const unsigned short h1 = f2bf(y[2 * i + 1]);
        const unsigned short l0 = f2bf(y[2 * i] - bf2f(h0));
        const unsigned short l1 = f2bf(y[2 * i + 1] - bf2f(h1));
        hv[i] = (unsigned int)h0 | ((unsigned int)h1 << 16);
        lv[i] = (unsigned int)l0 | ((unsigned int)l1 << 16);
    }
    uint4* dh = (uint4*)(hi + (size_t)row * DDIM + lane * 8);
    uint4* dl = (uint4*)(lo + (size_t)row * DDIM + lane * 8);
    *dh = make_uint4(hv[0], hv[1], hv[2], hv[3]);
    *dl = make_uint4(lv[0], lv[1], lv[2], lv[3]);
}

// Off-diag super-tile assignment table: code = SI*8+SJ (SI<SJ, 8x8 super
// grid over the 64x64 tile grid). XCD0-3: 3 supers each (idx xcd*3+sup);
// XCD4-7: 4 supers each (idx 12+(xcd-4)*4+sup). Greedy-balanced:
// XCD0-3 also carry 2 diagonal supers (36 tiles) -> 264 tiles; XCD4-7: 256.
__device__ __constant__ unsigned char OSUP[28] = {
    1, 2, 10,   3, 11, 19,   4, 12, 20,   28, 5, 13,
    21, 29, 37, 6,   14, 22, 30, 38,   46, 7, 15, 23,   31, 39, 47, 55};

// ---- k_simstats: symmetric, L2 super-tiled, co-staged, BK=32, 32KB LDS ----
// Fixed-reference softmax: Zref = sum exp(S-1) (S in [-1,1] -> exp in
// [.135,1]: no overflow/underflow, partials add plainly).
// 2112 blocks; bid%8 = XCD; each XCD owns whole 8x8 super-tiles (I fastest
// within a super: B-tile shared x8, super's A+B bands L2-resident).
// 128x128 tile, 4 waves 2x2, rt4 x ct4 16x16x32 frags; per K-chunk (BK=32)
// stage Ahi|Alo|Bhi|Blo (32 KB) and run hi*hi+hi*lo+lo*hi.
// launch_bounds (256,3): 170-reg unified budget. (256,4) = 128-reg budget
// SPILLS (R12: WRITE_SIZE 10->332 MB scratch traffic, MfmaUtil 34->18,
// +100 us). acc=64 + arch 64 leaves no headroom at 128. Do not raise.
//
// SESSION LEDGER (rounds 0-9, all refuted -- do NOT re-walk):
//  R1 64KB counted-vmcnt dbuf: 158us (occupancy 3->2 blk/CU, m132 mode)
//  R2 48KB 6-slot counted rotation @3blk/CU: 136.5us (== baseline)
//  R3 direct-global frag gather, no LDS: 347us (TA line-scatter, 16
//     lines/instr -> vector-mem front-end bound, MfmaUtil 12%)
//  R4-R6 256x128 8-wave m201-template ports (broken map / monolithic /
//     faithful phases): 165-178us, MfmaUtil 25-28% -- the 8-phase gate
//     does NOT transfer at BN=128 / 48-MFMA 3-pass chunks / 1 blk/CU
//  R8 grid.sync cooperative fusion: 604us (spin-wait storm across XCDs)
//  R9 last-contributor fusion w/ device fences: 416us (__threadfence =
//     L2 writeback/invalidate on CDNA4 -> supertile L2 residency destroyed)
// CONCLUSION: this 2-barrier drain at 3 blk/CU (34.5% MfmaUtil, ~131us)
// is the schedule optimum for this op; cross-block TLP beats every
// in-block pipeline that costs occupancy. total-simstats ~95us is launch
// boundaries + small kernels; both fusion vehicles measured dead on this
// chip. Untested levers: 32x32x16 MFMA shape; k_lossc scatter locality.
// Strict-upper tiles also emit col stats (mirror rows, S=S^T). Slot p of row
// i covers cols [p*128,(p+1)*128): row-stats->slot J, col-stats->slot I.
// Cross-lane merges: strict >/< without index tie-break (exact fp32 ties
// across lanes measure-zero; in-lane scan order preserves first-occurrence).
__global__ __launch_bounds__(256, 3) void k_simstats(
    const unsigned short* __restrict__ ghi, const unsigned short* __restrict__ glo,
    float* __restrict__ pmax, float* __restrict__ pmin, float* __restrict__ pZ,
    int* __restrict__ pamax, int* __restrict__ pamin) {
    // ---- tile mapping (block-uniform) ----
    const int bid = blockIdx.x;
    const int xcd = bid & 7;
    const int off = bid >> 3;
    int I, J;
    if (xcd < 4) {
        if (off < 72) {  // two diagonal supers: s = xcd*2 + (off>=36)
            const int s = xcd * 2 + (off >= 36);
            const int u = (off >= 36) ? off - 36 : off;
            int jj = 0;  // triangular: i<=j within the 8x8 super, i fastest
            while ((jj + 1) * (jj + 2) / 2 <= u) ++jj;
            const int ii = u - jj * (jj + 1) / 2;
            I = s * 8 + ii; J = s * 8 + jj;
        } else {
            const int sup = (off - 72) >> 6;
            const int u = (off - 72) & 63;
            const int code = OSUP[xcd * 3 + sup];
            I = (code >> 3) * 8 + (u & 7);   // I fastest: B-tile shared x8
            J = (code & 7) * 8 + (u >> 3);
        }
    } else {
        if (off >= 256) return;  // 32 pad blocks
        const int sup = off >> 6;
        const int u = off & 63;
        const int code = OSUP[12 + (xcd - 4) * 4 + sup];
        I = (code >> 3) * 8 + (u & 7);
        J = (code & 7) * 8 + (u >> 3);
    }

    __shared__ unsigned short SH[4 * BM * 32];  // 32 KB: Ahi|Alo|Bhi|Blo
    unsigned short* Ahi = SH;
    unsigned short* Alo = SH + 4096;
    unsigned short* Bhi = SH + 8192;
    unsigned short* Blo = SH + 12288;
    const int t = threadIdx.x;
    const int wave = t >> 6;
    const int lane = t & 63;
    const int lanelo = lane & 15;
    const int quad = lane >> 4;
    const int wr = wave & 1;
    const int wc = wave >> 1;

    // staging: per region thread t fills slots t*16 + q*4096 ->
    // (row = (t>>2)+64q, chunk-slot = t&3); src chunk = slot ^ ((row>>1)&3)
    const int srow = t >> 2;                             // 0..63
    const int scolb = ((t & 3) ^ ((t >> 3) & 3)) << 4;   // swizzled src chunk
    char* lAh = (char*)Ahi + t * 16;
    char* lAl = (char*)Alo + t * 16;
    char* lBh = (char*)Bhi + t * 16;
    char* lBl = (char*)Blo + t * 16;

    // frag-read slot (ushort units): quad ^ ((lanelo>>1)&3), loop-invariant
    const int fsl = (quad ^ ((lanelo >> 1) & 3)) << 3;
    const int aoff = (wr * 64 + lanelo) * 32 + fsl;  // + rt*16*32
    const int boff = (wc * 64 + lanelo) * 32 + fsl;  // + ct*16*32

    // epilogue LDS overlays (A half: row stats; B half: col stats)
    float* rm  = (float*)SH;            // [2 wc][128]
    float* rz  = rm + 256;
    float* rmn = rz + 256;
    int*   ra  = (int*)(rmn + 256);
    int*   ran = ra + 256;              // 5 KB < 8 KB (Ahi+Alo)
    float* cm  = (float*)Bhi;           // [2 wr][128]
    float* cz  = cm + 256;
    float* cmn = cz + 256;
    int*   ca  = (int*)(cmn + 256);
    int*   can = ca + 256;

    const int i0 = I * BM;
    const int j0 = J * BM;
    const bool isdiag = (I == J);

    f32x4 acc[4][4];
#pragma unroll
    for (int rt = 0; rt < 4; ++rt)
#pragma unroll
        for (int ct = 0; ct < 4; ++ct)
            acc[rt][ct] = (f32x4){0.f, 0.f, 0.f, 0.f};

    const char* baseAh = (const char*)ghi + (size_t)(i0 + srow) * 1024 + scolb;
    const char* baseAl = (const char*)glo + (size_t)(i0 + srow) * 1024 + scolb;
    const char* baseBh = (const char*)ghi + (size_t)(j0 + srow) * 1024 + scolb;
    const char* baseBl = (const char*)glo + (size_t)(j0 + srow) * 1024 + scolb;

    for (int k0 = 0; k0 < DDIM; k0 += 32) {
        __syncthreads();  // prior frag/epilogue LDS reads done
#pragma unroll
        for (int q = 0; q < 2; ++q) {
            const size_t roff = (size_t)q * 64 * 1024 + k0 * 2;
            gld16(baseAh + roff, lAh + q * 4096);
            gld16(baseAl + roff, lAl + q * 4096);
            gld16(baseBh + roff, lBh + q * 4096);
            gld16(baseBl + roff, lBl + q * 4096);
        }
        __syncthreads();  // drains vmcnt: staged data visible
        bf16x8 ah[4], al[4];
#pragma unroll
        for (int rt = 0; rt < 4; ++rt) {
            ah[rt] = *(const bf16x8*)&Ahi[aoff + rt * 512];
            al[rt] = *(const bf16x8*)&Alo[aoff + rt * 512];
        }
#pragma unroll
        for (int ct = 0; ct < 4; ++ct) {
            const bf16x8 bh = *(const bf16x8*)&Bhi[boff + ct * 512];
            const bf16x8 bl = *(const bf16x8*)&Blo[boff + ct * 512];
#pragma unroll
            for (int rt = 0; rt < 4; ++rt) {
                acc[rt][ct] = __builtin_amdgcn_mfma_f32_16x16x32_bf16(
                    ah[rt], bh, acc[rt][ct], 0, 0, 0);
                acc[rt][ct] = __builtin_amdgcn_mfma_f32_16x16x32_bf16(
                    ah[rt], bl, acc[rt][ct], 0, 0, 0);
                acc[rt][ct] = __builtin_amdgcn_mfma_f32_16x16x32_bf16(
                    al[rt], bh, acc[rt][ct], 0, 0, 0);
            }
        }
    }

    __syncthreads();  // all frag reads done before LDS overlay

    // ---- phase 1: row max/min (original acc) ----
    // C/D layout: col = lanelo, row = quad*4 + reg  [m89]
#pragma unroll
    for (int rt = 0; rt < 4; ++rt) {
#pragma unroll
        for (int r = 0; r < 4; ++r) {
            const int lrow = wr * 64 + rt * 16 + quad * 4 + r;
            float tmax = NEGF; int targ = 0;
            float tmin = POSF; int targn = 0;
            if (isdiag) {
                const int gi = i0 + lrow;
#pragma unroll
                for (int ct = 0; ct < 4; ++ct) {
                    const int gj = j0 + wc * 64 + ct * 16 + lanelo;
                    const float v = acc[rt][ct][r];
                    const bool dg = (gj == gi);
                    const float vM = dg ? NEGF : v;
                    const float vm = dg ? POSF : v;
                    if (vM > tmax) { tmax = vM; targ = gj; }  // ct asc = j asc
                    if (vm < tmin) { tmin = vm; targn = gj; }
                }
            } else {
#pragma unroll
                for (int ct = 0; ct < 4; ++ct) {
                    const int gj = j0 + wc * 64 + ct * 16 + lanelo;
                    const float v = acc[rt][ct][r];
                    if (v > tmax) { tmax = v; targ = gj; }
                    if (v < tmin) { tmin = v; targn = gj; }
                }
            }
#pragma unroll
            for (int msk = 1; msk < 16; msk <<= 1) {
                const float v2 = __shfl_xor(tmax, msk, 64);
                const int i2 = __shfl_xor(targ, msk, 64);
                if (v2 > tmax) { tmax = v2; targ = i2; }
                const float v3 = __shfl_xor(tmin, msk, 64);
                const int i3 = __shfl_xor(targn, msk, 64);
                if (v3 < tmin) { tmin = v3; targn = i3; }
            }
            if (lanelo == 0) {
                const int o = wc * 128 + lrow;
                rm[o] = tmax; rmn[o] = tmin;
                ra[o] = targ; ran[o] = targn;
            }
        }
    }

    // ---- phase 2: col max/min (strict-upper only, original acc) ----
    if (!isdiag) {
#pragma unroll
        for (int ct = 0; ct < 4; ++ct) {
            const int lcol = wc * 64 + ct * 16 + lanelo;
            float tmax = NEGF; int targ = 0;
            float tmin = POSF; int targn = 0;
#pragma unroll
            for (int rt = 0; rt < 4; ++rt)
#pragma unroll
                for (int r = 0; r < 4; ++r) {
                    const int gi = i0 + wr * 64 + rt * 16 + quad * 4 + r;
                    const float v = acc[rt][ct][r];
                    if (v > tmax) { tmax = v; targ = gi; }  // gi asc in (rt,r)
                    if (v < tmin) { tmin = v; targn = gi; }
                }
#pragma unroll
            for (int msk = 16; msk < 64; msk <<= 1) {
                const float m2 = __shfl_xor(tmax, msk, 64);
                const int i2 = __shfl_xor(targ, msk, 64);
                if (m2 > tmax) { tmax = m2; targ = i2; }
                const float mn2 = __shfl_xor(tmin, msk, 64);
                const int in2 = __shfl_xor(targn, msk, 64);
                if (mn2 < tmin) { tmin = mn2; targn = in2; }
            }
            if (quad == 0) {
                const int o = wr * 128 + lcol;
                cm[o] = tmax; cmn[o] = tmin;
                ca[o] = targ; can[o] = targn;
            }
        }
    }

    // ---- phase 3: acc <- exp(S-1); then zero the 16 diag entries ----
#pragma unroll
    for (int rt = 0; rt < 4; ++rt)
#pragma unroll
        for (int ct = 0; ct < 4; ++ct)
#pragma unroll
            for (int r = 0; r < 4; ++r)
                acc[rt][ct][r] = __expf(acc[rt][ct][r] - 1.f);
    if (isdiag && wr == wc) {
#pragma unroll
        for (int rt = 0; rt < 4; ++rt)
#pragma unroll
            for (int r = 0; r < 4; ++r)
                if (lanelo == quad * 4 + r) acc[rt][rt][r] = 0.f;
    }

    // ---- phase 4: row Zref sums ----
#pragma unroll
    for (int rt = 0; rt < 4; ++rt)
#pragma unroll
        for (int r = 0; r < 4; ++r) {
            float s = acc[rt][0][r] + acc[rt][1][r] +
                      acc[rt][2][r] + acc[rt][3][r];
#pragma unroll
            for (int msk = 1; msk < 16; msk <<= 1) s += __shfl_xor(s, msk, 64);
            if (lanelo == 0)
                rz[wc * 128 + wr * 64 + rt * 16 + quad * 4 + r] = s;
        }

    // ---- phase 5: col Zref sums (strict-upper only) ----
    if (!isdiag) {
#pragma unroll
        for (int ct = 0; ct < 4; ++ct) {
            float s = 0.f;
#pragma unroll
            for (int rt = 0; rt < 4; ++rt)
                s += acc[rt][ct][0] + acc[rt][ct][1] +
                     acc[rt][ct][2] + acc[rt][ct][3];
#pragma unroll
            for (int msk = 16; msk < 64; msk <<= 1) s += __shfl_xor(s, msk, 64);
            if (quad == 0)
                cz[wr * 128 + wc * 64 + ct * 16 + lanelo] = s;
        }
    }

    __syncthreads();

    if (t < BM) {
        // merge row-stat wc-halves (wc0 cols < wc1): row i0+t, slot J
        const float m0 = rm[t], m1 = rm[128 + t];
        float vmax = m0; int imax = ra[t];
        if (m1 > vmax) { vmax = m1; imax = ra[128 + t]; }
        float vmin = rmn[t]; int imin = ran[t];
        if (rmn[128 + t] < vmin) { vmin = rmn[128 + t]; imin = ran[128 + t]; }
        const size_t o = (size_t)J * CDIM + i0 + t;
        pmax[o] = vmax; pmin[o] = vmin; pZ[o] = rz[t] + rz[128 + t];
        pamax[o] = imax; pamin[o] = imin;
    } else if (!isdiag) {
        // merge col-stat wr-halves (wr0 rows < wr1): row j0+tt, slot I
        const int tt = t - BM;
        const float m0 = cm[tt], m1 = cm[128 + tt];
        float vmax = m0; int imax = ca[tt];
        if (m1 > vmax) { vmax = m1; imax = ca[128 + tt]; }
        float vmin = cmn[tt]; int imin = can[tt];
        if (cmn[128 + tt] < vmin) { vmin = cmn[128 + tt]; imin = can[128 + tt]; }
        const size_t o = (size_t)I * CDIM + j0 + tt;
        pmax[o] = vmax; pmin[o] = vmin; pZ[o] = cz[tt] + cz[128 + tt];
        pamax[o] = imax; pamin[o] = imin;
    }
}

// ---- k_lossc: fused partial-merge + triplet distance, one wave per row ----
// lane p owns slot p (cols [p*128,(p+1)*128)); consecutive rows (waves in a
// block) share the same cache lines of each partial array. Butterfly over 64
// lanes merges max/argmax/min/argmin/Z (strict compares: exact cross-slot
// fp32 ties are measure-zero; within-slot order already first-occurrence).
__global__ __launch_bounds__(256) void k_lossc(
    const float* __restrict__ pmax, const float* __restrict__ pmin,
    const float* __restrict__ pZ, const int* __restrict__ pamax,
    const int* __restrict__ pamin, const float* __restrict__ w,
    float* __restrict__ vals) {
    const int wave = threadIdx.x >> 6;
    const int lane = threadIdx.x & 63;
    const int row = blockIdx.x * 4 + wave;
    const size_t o = (size_t)lane * CDIM + row;
    float v = pmax[o]; int a = pamax[o];
    float u = pmin[o]; int b = pamin[o];
    float z = pZ[o];
#pragma unroll
    for (int msk = 1; msk < 64; msk <<= 1) {
        const float v2 = __shfl_xor(v, msk, 64);
        const int i2 = __shfl_xor(a, msk, 64);
        if (v2 > v) { v = v2; a = i2; }
        const float v3 = __shfl_xor(u, msk, 64);
        const int i3 = __shfl_xor(b, msk, 64);
        if (v3 < u) { u = v3; b = i3; }
        z += __shfl_xor(z, msk, 64);
    }
    // P[ms]-P[ls] = (1 - exp(mn-M)) * exp(M-1) / Zref
    const float margin = (1.f - __expf(u - v)) * __expf(v - 1.f) / z;
    const int jm = a, jl = b;

    const float4* wi = (const float4*)(w + (size_t)row * DDIM);
    const float4* wm = (const float4*)(w + (size_t)jm * DDIM);
    const float4* wl = (const float4*)(w + (size_t)jl * DDIM);
    float sm = 0.f, sl = 0.f;
#pragma unroll
    for (int h = 0; h < 2; ++h) {
        const int idx = h * 64 + lane;
        const float4 x = wi[idx];
        const float4 y = wm[idx];
        const float4 c = wl[idx];
        float d;
        d = x.x - y.x; sm = fmaf(d, d, sm);
        d = x.y - y.y; sm = fmaf(d, d, sm);
        d = x.z - y.z; sm = fmaf(d, d, sm);
        d = x.w - y.w; sm = fmaf(d, d, sm);
        d = x.x - c.x; sl = fmaf(d, d, sl);
        d = x.y - c.y; sl = fmaf(d, d, sl);
        d = x.z - c.z; sl = fmaf(d, d, sl);
        d = x.w - c.w; sl = fmaf(d, d, sl);
    }
#pragma unroll
    for (int msk = 1; msk < 64; msk <<= 1) {
        sm += __shfl_xor(sm, msk, 64);
        sl += __shfl_xor(sl, msk, 64);
    }
    if (lane == 0) {
        const float val = sqrtf(sm) - sqrtf(sl) + margin;
        vals[row] = val > 0.f ? val : 0.f;
    }
}

// ---- k_final: deterministic fixed-order mean (no atomics) ----
__global__ __launch_bounds__(256) void k_final(const float* __restrict__ vals,
                                               float* __restrict__ out) {
    __shared__ float red[256];
    float s = 0.f;
    for (int i = threadIdx.x; i < CDIM; i += 256) s += vals[i];
    red[threadIdx.x] = s;
    __syncthreads();
#pragma unroll
    for (int k = 128; k > 0; k >>= 1) {
        if (threadIdx.x < (unsigned)k) red[threadIdx.x] += red[threadIdx.x + k];
        __syncthreads();
    }
    if (threadIdx.x == 0) out[0] = red[0] * (1.0f / CDIM);
}

extern "C" void kernel_launch(void* const* d_in, const int* in_sizes, int n_in,
                              void* d_out, int out_size, void* d_ws, size_t ws_size,
                              hipStream_t stream) {
    const float* g = (const float*)d_in[0];  // gt_class_embeddings [8192,512]
    const float* w = (const float*)d_in[1];  // w [8192,512]
    float* out = (float*)d_out;

    // workspace layout (~26.6 MB)
    unsigned short* ghi = (unsigned short*)d_ws;
    unsigned short* glo = ghi + (size_t)CDIM * DDIM;
    float* p = (float*)(glo + (size_t)CDIM * DDIM);
    float* pmax = p;      p += (size_t)NSLOT * CDIM;
    float* pmin = p;      p += (size_t)NSLOT * CDIM;
    float* pZ = p;        p += (size_t)NSLOT * CDIM;
    int* pamax = (int*)p; p += (size_t)NSLOT * CDIM;
    int* pamin = (int*)p; p += (size_t)NSLOT * CDIM;
    float* vals = p;      p += CDIM;

    k_prep<<<CDIM / 4, 256, 0, stream>>>(g, ghi, glo);
    k_simstats<<<2112, 256, 0, stream>>>(ghi, glo, pmax, pmin, pZ, pamax, pamin);
    k_lossc<<<CDIM / 4, 256, 0, stream>>>(pmax, pmin, pZ, pamax, pamin, w, vals);
    k_final<<<1, 256, 0, stream>>>(vals, out);
}